// Round 12
// baseline (81.336 us; speedup 1.0000x reference)
//
#include <hip/hip_runtime.h>
#include <math.h>

#define NQ 12
#define TPB 256

// R22: REMOVE op_sel-MODIFIED VOP3P FROM THE HOT LOOP. Surviving theory
// after R12-R21: modifier-laden v_pk_*_f32 (op_sel/op_sel_hi/neg -- ~75%
// of the 1152 gate ops in EVERY version since baseline) occupies the f32
// pipe ~12-16 cyc instead of 4 on gfx950. Fits exactly: R16 solo 10.8us
// (864x16+288x4 ~= 16k cyc + DS), VALUBusy 20-25% (issue cycles <<
// occupancy), R12 proportional, R20 pipelining null (throughput not
// latency), TLP null (same slow ops from all waves). Fix: gates in plain
// scalar C (16 FMA-contractable ops per M pair, 8 per RY pair) -- scalar
// v_fma_f32 is a DOCUMENTED 2-cyc op. Same VALU occupancy as 4-cyc pk,
// strictly better if the penalty is real; compiler schedules freely.
// Structure = R19 (best verified); R21 sleep removed.
//
// Amp index j (12 bits), qubit q <-> j bit 11-q. Register layouts
// (t = thread 0..255 gives 8 bits, r = reg index 4 bits):
//   A: j = (r<<8)|t                  r = j[11:8] = qubits 0..3
//   B: j = (t[7:4]<<8)|(r<<4)|t[3:0] r = j[7:4]  = qubits 4..7
//   C: j = (t<<4)|r                  r = j[3:0]  = qubits 8..11
// B,C share wave bits j[11:10] -> B<->C roundtrips wave-local.
// Swizzle sg(j) = (j&~15)|((j^(j>>4)^(j>>8))&15); with kC=(t^(t>>4))&15:
//   sg(J_A(r)) = VA ^ 257r,  VA = (t&0xF0)|kC
//   sg(J_B(r)) = VB ^ 17r,   VB = ((t>>4)<<8)|kC
//   sg(J_C(r)) = VC ^ r,     VC = (t<<4)|kC
//   sg(P(j))   = Ft ^ G(r<<8), Ft per-thread, G const-folded
//
// Gate algebra (verified R2-R19): SU(2) [[a,-conj b],[b,conj a]],
// a=(ax,ay), b=(bx,by):
//   n0 = a*v0 - conj(b)*v1:
//     n0.x = ax x0 - ay y0 - bx x1 - by y1
//     n0.y = ax y0 + ay x0 - bx y1 + by x1
//   n1 = b*v0 + conj(a)*v1:
//     n1.x = bx x0 - by y0 + ax x1 + ay y1
//     n1.y = bx y0 + by x0 + ax y1 - ay x1
//   RY(c,s): n0 = c v0 - s v1 ; n1 = s v0 + c v1
//
// Circuit (algebra verified R2-R10): init(C) = L0 RX product state with
// ring0 FOLDED via inverse perm; fused M_q = RX(L1)*RZ(L0)*RY(L0); ring1
// scatter; L1 RY (final RZ dropped); <Z_q> via partial reg-WHT + 6-stage
// lane-WHT butterfly.

// variadic: commas inside the body are re-joined by __VA_ARGS__
#define FOR_PAIRS4(RB, ...) do {                                      \
    const int msk_ = 1 << (RB);                                       \
    _Pragma("unroll")                                                 \
    for (int h_ = 0; h_ < 8; ++h_) {                                  \
        const int i0 = ((h_ & ~(msk_ - 1)) << 1) | (h_ & (msk_ - 1)); \
        const int i1 = i0 | msk_;                                     \
        __VA_ARGS__;                                                  \
    } } while (0)

// strength-reduced swizzled addresses (VA/VB/VC in scope)
#define ADDR_A(r) (VA ^ (257 * (r)))
#define ADDR_B(r) (VB ^ (17 * (r)))
#define ADDR_C(r) (VC ^ (r))

// compiler-only fence for the barrier-less wave-local store->load aliasing
#define CFENCE asm volatile("" ::: "memory")

// wave-local roundtrip (same-wave LDS ordering, no barrier)
#define LOCAL_X(AS, AD) do {                                          \
    _Pragma("unroll")                                                 \
    for (int r_ = 0; r_ < 16; ++r_) S[AS(r_)] = v[r_];                \
    CFENCE;                                                           \
    _Pragma("unroll")                                                 \
    for (int r_ = 0; r_ < 16; ++r_) v[r_] = S[AD(r_)];                \
  } while (0)

// SU(2) gate, plain scalar C (compiler contracts to v_fma_f32 chains)
#define M_GATE(q, RB) do {                                            \
        const float ax = GA[q].x, ay = GA[q].y;                       \
        const float bx = GB[q].x, by = GB[q].y;                       \
        FOR_PAIRS4(RB,                                                \
            const float x0 = v[i0].x;                                 \
            const float y0 = v[i0].y;                                 \
            const float x1 = v[i1].x;                                 \
            const float y1 = v[i1].y;                                 \
            v[i0].x = ax*x0 - ay*y0 - bx*x1 - by*y1;                  \
            v[i0].y = ax*y0 + ay*x0 - bx*y1 + by*x1;                  \
            v[i1].x = bx*x0 - by*y0 + ax*x1 + ay*y1;                  \
            v[i1].y = bx*y0 + by*x0 + ax*y1 - ay*x1;                  \
        );                                                            \
    } while (0)

#define RY_GATE(q, RB) do {                                           \
        const float cc = GY[q].x, ss = GY[q].y;                       \
        FOR_PAIRS4(RB,                                                \
            const float x0 = v[i0].x;                                 \
            const float y0 = v[i0].y;                                 \
            const float x1 = v[i1].x;                                 \
            const float y1 = v[i1].y;                                 \
            v[i0].x = cc*x0 - ss*x1;                                  \
            v[i0].y = cc*y0 - ss*y1;                                  \
            v[i1].x = ss*x0 + cc*x1;                                  \
            v[i1].y = ss*y0 + cc*y1;                                  \
        );                                                            \
    } while (0)

// phase: gate qubit QB+d on r-bit 3-d (holds for A, B, C alike)
#define M_PHASE(QB)  do { _Pragma("unroll")                                 \
    for (int d_ = 0; d_ < 4; ++d_) M_GATE((QB) + d_, 3 - d_); } while (0)
#define RY_PHASE(QB) do { _Pragma("unroll")                                 \
    for (int d_ = 0; d_ < 4; ++d_) RY_GATE((QB) + d_, 3 - d_); } while (0)

__global__ __launch_bounds__(TPB, 2) void vqc_kernel(
    const float* __restrict__ x,    // [B, 12]
    const float* __restrict__ th,   // [2, 12, 2]
    const float* __restrict__ lm,   // [2, 12]
    float* __restrict__ out)        // [B, 12]
{
    __shared__ float2 S[4096];
    __shared__ float2 gmA[12];      // fused M gate: (ax, ay)
    __shared__ float2 gmB[12];      // fused M gate: (bx, by)
    __shared__ float2 gyS[12];      // L1 RY: (c, s)
    __shared__ float2 coI[12];      // L0 RX half-angle (c,s)
    __shared__ float red[4 * 12];

    const int b = blockIdx.x;
    const int t = threadIdx.x;
    const int l = t & 63;
    const int w = t >> 6;

    // strength-reduced address bases
    const int kC = (t ^ (t >> 4)) & 15;
    const int VA = (t & 0xF0) | kC;
    const int VB = ((t >> 4) << 8) | kC;
    const int VC = (t << 4) | kC;
    // ring per-thread part: Ft = sg(P-image of t) (GF(2)-linear split)
    int Ft;
    {
        int yt = t ^ (t >> 1); yt ^= yt >> 2; yt ^= yt >> 4; yt ^= yt >> 8;
        int pt = (yt & 0x7FF) | ((__popc(t) & 1) << 11);
        Ft = (pt & ~15) | ((pt ^ (pt >> 4) ^ (pt >> 8)) & 15);
    }

    // ---- cooperative coefficient precompute ----
    if (t < 12) {
        float h = 0.5f * lm[t] * x[b * NQ + t];
        float c, s; __sincosf(h, &s, &c);
        coI[t] = make_float2(c, s);
    } else if (t < 24) {
        int q = t - 12;
        float h = 0.5f * th[24 + 2 * q];
        float c, s; __sincosf(h, &s, &c);
        gyS[q] = make_float2(c, s);
    } else if (t < 36) {
        int q = t - 24;
        float ha = 0.5f * lm[12 + q] * x[b * NQ + q];  // L1 RX half
        float hy = 0.5f * th[2 * q];                   // L0 RY half
        float hz = 0.5f * th[2 * q + 1];               // L0 RZ half
        float ca, sa, cy, sy, cz, sz;
        __sincosf(ha, &sa, &ca);
        __sincosf(hy, &sy, &cy);
        __sincosf(hz, &sz, &cz);
        // M = RX(a) RZ(z) RY(y) in SU(2): alpha = M00, beta = M10 (R9-verified)
        float ax = ca*cy*cz + sa*sy*sz;
        float ay = -(ca*cy*sz + sa*sy*cz);
        float bx = ca*sy*cz - sa*cy*sz;
        float by = ca*sy*sz - sa*cy*cz;
        gmA[q] = make_float2(ax, ay);
        gmB[q] = make_float2(bx, by);
    }
    __syncthreads();                                   // B1

    // ---- hoist gate constants (compiler chooses regs vs rematerialize) --
    float2 GA[12], GB[12], GY[12];
#pragma unroll
    for (int q = 0; q < 12; ++q) {
        GA[q] = gmA[q];
        GB[q] = gmB[q];
        GY[q] = gyS[q];
    }

    float2 v[16];

    // ---- init in layout C: L0 RX product state, ring0 folded ----
    // (R10-verified) i = P^{-1}(j), j = (t<<4)|r:
    //  i0=r0^r1 (q11), i1=r1^r2 (q10), i2=r2^r3 (q9), i3=r3^t0 (q8),
    //  i4..i9 = gray(t) bits 0..5 (qubits 7..2),
    //  i10 = t6^r0^t7 (q1), i11 = r0^t7 (q0)
    {
        const int g = (t ^ (t >> 1)) & 0x3F;
        float Pt = 1.0f;
#pragma unroll
        for (int m = 0; m < 6; ++m) {
            float2 cs = coI[7 - m];
            Pt *= ((g >> m) & 1) ? cs.y : cs.x;
        }
        const int ct = __popc(g);
        const int t0 = t & 1, t7 = (t >> 7) & 1;
        const int e1 = ((t >> 6) ^ (t >> 7)) & 1;
        float2 q11 = coI[11], q10 = coI[10], q9 = coI[9],
               q8 = coI[8], q1 = coI[1], q0 = coI[0];
        const float u8  = t0 ? q8.y : q8.x;     // qubit 8, key t0^r3
        const float u8n = t0 ? q8.x : q8.y;
        const float u1  = e1 ? q1.y : q1.x;     // qubit 1, key e1^r0
        const float u1n = e1 ? q1.x : q1.y;
        const float u0  = t7 ? q0.y : q0.x;     // qubit 0, key t7^r0
        const float u0n = t7 ? q0.x : q0.y;
#pragma unroll
        for (int r = 0; r < 16; ++r) {
            const int r0 = r & 1, r1 = (r >> 1) & 1, r2 = (r >> 2) & 1,
                      r3 = (r >> 3) & 1;
            const int b11 = r0 ^ r1, b10 = r1 ^ r2, b9 = r2 ^ r3;
            float m = Pt * (b11 ? q11.y : q11.x) * (b10 ? q10.y : q10.x)
                         * (b9 ? q9.y : q9.x) * (r3 ? u8n : u8)
                         * (r0 ? u1n : u1) * (r0 ? u0n : u0);
            int k = (ct + b11 + b10 + b9 + (r3 ^ t0) + (r0 ^ e1) + (r0 ^ t7)) & 3;
            v[r].x = (k == 0) ? m : ((k == 2) ? -m : 0.0f);
            v[r].y = (k == 3) ? m : ((k == 1) ? -m : 0.0f);
        }
    }

    // ---- fused M-pass (L0 RY,RZ + L1 RX), C -> B -> A ----
    M_PHASE(8);                       // qubits 8..11 in C
    LOCAL_X(ADDR_C, ADDR_B);          // X1: wave-local
    M_PHASE(4);                       // qubits 4..7  in B
#pragma unroll
    for (int r = 0; r < 16; ++r) S[ADDR_B(r)] = v[r];
    __syncthreads();                  // B2 (cross B -> A)
#pragma unroll
    for (int r = 0; r < 16; ++r) v[r] = S[ADDR_A(r)];
    M_PHASE(0);                       // qubits 0..3  in A

    // ---- layer-1 CNOT ring: A -> A (addr = Ft ^ const-folded G(r<<8)) ----
    __syncthreads();                  // B3 (all A-reads done before scatter)
#pragma unroll
    for (int r = 0; r < 16; ++r) {
        const int jr = r << 8;
        int yr = jr ^ (jr >> 1); yr ^= yr >> 2; yr ^= yr >> 4; yr ^= yr >> 8;
        const int pr = (yr & 0x7FF) | (((__popc(jr) ^ (jr >> 11)) & 1) << 11);
        const int Gr = (pr & ~15) | ((pr ^ (pr >> 4) ^ (pr >> 8)) & 15);
        S[Ft ^ Gr] = v[r];
    }
    __syncthreads();                  // B4
#pragma unroll
    for (int r = 0; r < 16; ++r) v[r] = S[ADDR_A(r)];

    // ---- layer-1 RY (final RZ dropped), A -> B -> C ----
    RY_PHASE(0);                      // in A
    // no barrier: store hits exactly the addresses THIS thread read at the
    // B4 gather; no other thread touches these slots (R2-verified).
#pragma unroll
    for (int r = 0; r < 16; ++r) S[ADDR_A(r)] = v[r];
    __syncthreads();                  // B5 (cross A -> B)
#pragma unroll
    for (int r = 0; r < 16; ++r) v[r] = S[ADDR_B(r)];
    RY_PHASE(4);                      // in B
    LOCAL_X(ADDR_B, ADDR_C);          // X5: wave-local
    RY_PHASE(8);                      // in C

    // ---- measurement in C ----
    // qubits 8..11 <-> r bits 3..0 ; qubits 2..7 <-> lane bits 5..0
    // (lane bit k = j[4+k] = qubit 7-k) ; qubits 0,1 <-> wave bits 1,0
    float p[16];
#pragma unroll
    for (int r = 0; r < 16; ++r)
        p[r] = fmaf(v[r].x, v[r].x, v[r].y * v[r].y);
    float sA[8], dA[8];
#pragma unroll
    for (int k = 0; k < 8; ++k) {
        sA[k] = p[2 * k] + p[2 * k + 1];
        dA[k] = p[2 * k] - p[2 * k + 1];
    }
    float z11 = ((dA[0] + dA[1]) + (dA[2] + dA[3]))
              + ((dA[4] + dA[5]) + (dA[6] + dA[7]));
    float sC[4], dC[4];
#pragma unroll
    for (int k = 0; k < 4; ++k) {
        sC[k] = sA[2 * k] + sA[2 * k + 1];
        dC[k] = sA[2 * k] - sA[2 * k + 1];
    }
    float z10 = (dC[0] + dC[1]) + (dC[2] + dC[3]);
    float e0 = sC[0] + sC[1], f0 = sC[0] - sC[1];
    float e1s = sC[2] + sC[3], f1 = sC[2] - sC[3];
    float vals[5];
    vals[0] = e0 + e1s;               // ptot
    vals[1] = e0 - e1s;               // z8  (r bit3)
    vals[2] = f0 + f1;                // z9  (r bit2)
    vals[3] = z10;                    // z10 (r bit1)
    vals[4] = z11;                    // z11 (r bit0)

    // 6-stage WHT butterfly: lane L ends with sum_l (-1)^{popc(L&l)} x_l
#pragma unroll
    for (int k = 0; k < 6; ++k) {
        const float sgn = ((l >> k) & 1) ? -1.f : 1.f;
#pragma unroll
        for (int m = 0; m < 5; ++m) {
            float tmp = __shfl_xor(vals[m], 1 << k, 64);
            vals[m] = fmaf(sgn, vals[m], tmp);
        }
    }
    if (l == 0) {                     // wave totals
        red[w * 12 + 0]  = vals[0];   // ptot (for qubits 0,1)
        red[w * 12 + 8]  = vals[1];
        red[w * 12 + 9]  = vals[2];
        red[w * 12 + 10] = vals[3];
        red[w * 12 + 11] = vals[4];
    } else if (__popc(l) == 1) {      // lane-bit sums: qubits 2..7
        int q = 8 - __ffs(l);         // l=1<<k -> q = 7-k
        red[w * 12 + q] = vals[0];
    }
    __syncthreads();                  // B6
    if (t < NQ) {
        float acc = 0.f;
#pragma unroll
        for (int ww = 0; ww < 4; ++ww) {
            if (t < 2) {
                float pv = red[ww * 12 + 0];
                acc += ((ww >> (1 - t)) & 1) ? -pv : pv;
            } else {
                acc += red[ww * 12 + t];
            }
        }
        out[b * NQ + t] = acc;
    }
}

extern "C" void kernel_launch(void* const* d_in, const int* in_sizes, int n_in,
                              void* d_out, int out_size, void* d_ws, size_t ws_size,
                              hipStream_t stream) {
    const int B = in_sizes[0] / NQ;  // 1024
    vqc_kernel<<<B, TPB, 0, stream>>>((const float*)d_in[0],
                                      (const float*)d_in[1],
                                      (const float*)d_in[2],
                                      (float*)d_out);
}

// Round 13
// 72.280 us; speedup vs baseline: 1.1253x; 1.1253x over previous
//
#include <hip/hip_runtime.h>
#include <math.h>

#define NQ 12
#define TPB 256

// R23: FORCED GATE-CONSTANT HOIST (opaque register pin). R21/R16 profiles
// show VGPR_Count=72/64 -- R19's hoist NEVER materialized: the compiler
// rematerializes gate constants by re-issuing LDS broadcast loads at every
// gate (legal: distinct LDS objects, unmodified after B1). So the per-gate
// lgkmcnt-wait theory was never tested; R19's null is void. It fits all
// black-box data: ~60 serial broadcast-load waits x ~120+cyc ~= the
// missing ~20k cyc; TLP null (all waves wait at the same loads); R20
// pipelining null (wait precedes math); R12/R22 op-count proportionality.
// Fix: after the hoist copy, pass each constant through asm("":"+v"(..)) --
// value becomes opaque, reload impossible, must stay in VGPRs. Budget
// 32 state + 72 const + ~15 temps ~= 119 < 256 cap of (256,2).
// Everything else byte-identical to R19 (verified, absmax 9.8e-4).
//
// Amp index j (12 bits), qubit q <-> j bit 11-q. Register layouts
// (t = thread 0..255 gives 8 bits, r = reg index 4 bits):
//   A: j = (r<<8)|t                  r = j[11:8] = qubits 0..3
//   B: j = (t[7:4]<<8)|(r<<4)|t[3:0] r = j[7:4]  = qubits 4..7
//   C: j = (t<<4)|r                  r = j[3:0]  = qubits 8..11
// B,C share wave bits j[11:10] -> B<->C roundtrips wave-local.
// Swizzle sg(j) = (j&~15)|((j^(j>>4)^(j>>8))&15); with kC=(t^(t>>4))&15:
//   sg(J_A(r)) = VA ^ 257r,  VA = (t&0xF0)|kC
//   sg(J_B(r)) = VB ^ 17r,   VB = ((t>>4)<<8)|kC
//   sg(J_C(r)) = VC ^ r,     VC = (t<<4)|kC
//   sg(P(j))   = Ft ^ G(r<<8), Ft per-thread, G const-folded
//
// Gate algebra (SU(2) [[a,-conj b],[b,conj a]], a=(ax,ay), b=(bx,by),
// A2=(ax,ay), B2=(bx,by) packed; per-term word-select, R19-verified):
//  n0 = a*v0 - conj(b)*v1 ; n1 = b*v0 + conj(a)*v1
//  RY (Y2=(c,s)): n0 = c*v0 - s*v1 ; n1 = s*v0 + c*v1
//
// Circuit (algebra verified R2-R10): init(C) = L0 RX product state with
// ring0 FOLDED via inverse perm; fused M_q = RX(L1)*RZ(L0)*RY(L0); ring1
// scatter; L1 RY (final RZ dropped); <Z_q> via partial reg-WHT + 6-stage
// lane-WHT butterfly.

#define PKMUL(d, a, b, MODS)                                          \
    asm("v_pk_mul_f32 %0, %1, %2 " MODS                               \
        : "=v"(d) : "v"(a), "v"(b))
#define PKFMA(d, a, b, c, MODS)                                       \
    asm("v_pk_fma_f32 %0, %1, %2, %3 " MODS                           \
        : "=v"(d) : "v"(a), "v"(b), "v"(c))

// opaque register pin: severs the value's link to its LDS source so the
// compiler cannot rematerialize-by-reload; forces VGPR residency.
#define PIN(f2) asm("" : "+v"(f2))

// variadic: commas inside the body are re-joined by __VA_ARGS__
#define FOR_PAIRS4(RB, ...) do {                                      \
    const int msk_ = 1 << (RB);                                       \
    _Pragma("unroll")                                                 \
    for (int h_ = 0; h_ < 8; ++h_) {                                  \
        const int i0 = ((h_ & ~(msk_ - 1)) << 1) | (h_ & (msk_ - 1)); \
        const int i1 = i0 | msk_;                                     \
        __VA_ARGS__;                                                  \
    } } while (0)

// strength-reduced swizzled addresses (VA/VB/VC in scope)
#define ADDR_A(r) (VA ^ (257 * (r)))
#define ADDR_B(r) (VB ^ (17 * (r)))
#define ADDR_C(r) (VC ^ (r))

// compiler-only fence for the barrier-less wave-local store->load aliasing
#define CFENCE asm volatile("" ::: "memory")

// wave-local roundtrip (same-wave LDS ordering, no barrier)
#define LOCAL_X(AS, AD) do {                                          \
    _Pragma("unroll")                                                 \
    for (int r_ = 0; r_ < 16; ++r_) S[AS(r_)] = v[r_];                \
    CFENCE;                                                           \
    _Pragma("unroll")                                                 \
    for (int r_ = 0; r_ < 16; ++r_) v[r_] = S[AD(r_)];                \
  } while (0)

// SU(2) gate from register-resident packed constants (R19-verified MODS)
#define M_GATE(q, RB) do {                                                  \
        const float2 A2 = GA[q];                                            \
        const float2 B2 = GB[q];                                            \
        FOR_PAIRS4(RB,                                                      \
            const float2 a0 = v[i0];                                        \
            const float2 a1 = v[i1];                                        \
            float2 t, u;                                                    \
            PKMUL(t, a0, A2, "op_sel_hi:[1,0]");                            \
            PKFMA(t, a0, A2, t,                                             \
                  "op_sel:[1,1,0] op_sel_hi:[0,1,1] neg_lo:[0,1,0]");       \
            PKFMA(t, a1, B2, t,                                             \
                  "op_sel_hi:[1,0,1] neg_lo:[0,1,0] neg_hi:[0,1,0]");       \
            PKFMA(t, a1, B2, t,                                             \
                  "op_sel:[1,1,0] op_sel_hi:[0,1,1] neg_lo:[0,1,0]");       \
            PKMUL(u, a0, B2, "op_sel_hi:[1,0]");                            \
            PKFMA(u, a0, B2, u,                                             \
                  "op_sel:[1,1,0] op_sel_hi:[0,1,1] neg_lo:[0,1,0]");       \
            PKFMA(u, a1, A2, u, "op_sel_hi:[1,0,1]");                       \
            PKFMA(u, a1, A2, u,                                             \
                  "op_sel:[1,1,0] op_sel_hi:[0,1,1] neg_hi:[0,1,0]");       \
            v[i0] = t; v[i1] = u;                                           \
        );                                                                  \
    } while (0)

#define RY_GATE(q, RB) do {                                                 \
        const float2 Y2 = GY[q];                                            \
        FOR_PAIRS4(RB,                                                      \
            float2 t, u;                                                    \
            PKMUL(t, v[i0], Y2, "op_sel_hi:[1,0]");                         \
            PKFMA(t, v[i1], Y2, t,                                          \
                  "op_sel:[0,1,0] op_sel_hi:[1,1,1] "                       \
                  "neg_lo:[0,1,0] neg_hi:[0,1,0]");                         \
            PKMUL(u, v[i0], Y2, "op_sel:[0,1] op_sel_hi:[1,1]");            \
            PKFMA(u, v[i1], Y2, u, "op_sel_hi:[1,0,1]");                    \
            v[i0] = t; v[i1] = u;                                           \
        );                                                                  \
    } while (0)

// phase: gate qubit QB+d on r-bit 3-d (holds for A, B, C alike)
#define M_PHASE(QB)  do { _Pragma("unroll")                                 \
    for (int d_ = 0; d_ < 4; ++d_) M_GATE((QB) + d_, 3 - d_); } while (0)
#define RY_PHASE(QB) do { _Pragma("unroll")                                 \
    for (int d_ = 0; d_ < 4; ++d_) RY_GATE((QB) + d_, 3 - d_); } while (0)

__global__ __launch_bounds__(TPB, 2) void vqc_kernel(
    const float* __restrict__ x,    // [B, 12]
    const float* __restrict__ th,   // [2, 12, 2]
    const float* __restrict__ lm,   // [2, 12]
    float* __restrict__ out)        // [B, 12]
{
    __shared__ float2 S[4096];
    __shared__ float2 gmA[12];      // fused M gate: (ax, ay)
    __shared__ float2 gmB[12];      // fused M gate: (bx, by)
    __shared__ float2 gyS[12];      // L1 RY: (c, s)
    __shared__ float2 coI[12];      // L0 RX half-angle (c,s)
    __shared__ float red[4 * 12];

    const int b = blockIdx.x;
    const int t = threadIdx.x;
    const int l = t & 63;
    const int w = t >> 6;

    // strength-reduced address bases
    const int kC = (t ^ (t >> 4)) & 15;
    const int VA = (t & 0xF0) | kC;
    const int VB = ((t >> 4) << 8) | kC;
    const int VC = (t << 4) | kC;
    // ring per-thread part: Ft = sg(P-image of t) (GF(2)-linear split)
    int Ft;
    {
        int yt = t ^ (t >> 1); yt ^= yt >> 2; yt ^= yt >> 4; yt ^= yt >> 8;
        int pt = (yt & 0x7FF) | ((__popc(t) & 1) << 11);
        Ft = (pt & ~15) | ((pt ^ (pt >> 4) ^ (pt >> 8)) & 15);
    }

    // ---- cooperative coefficient precompute ----
    if (t < 12) {
        float h = 0.5f * lm[t] * x[b * NQ + t];
        float c, s; __sincosf(h, &s, &c);
        coI[t] = make_float2(c, s);
    } else if (t < 24) {
        int q = t - 12;
        float h = 0.5f * th[24 + 2 * q];
        float c, s; __sincosf(h, &s, &c);
        gyS[q] = make_float2(c, s);
    } else if (t < 36) {
        int q = t - 24;
        float ha = 0.5f * lm[12 + q] * x[b * NQ + q];  // L1 RX half
        float hy = 0.5f * th[2 * q];                   // L0 RY half
        float hz = 0.5f * th[2 * q + 1];               // L0 RZ half
        float ca, sa, cy, sy, cz, sz;
        __sincosf(ha, &sa, &ca);
        __sincosf(hy, &sy, &cy);
        __sincosf(hz, &sz, &cz);
        // M = RX(a) RZ(z) RY(y) in SU(2): alpha = M00, beta = M10 (R9-verified)
        float ax = ca*cy*cz + sa*sy*sz;
        float ay = -(ca*cy*sz + sa*sy*cz);
        float bx = ca*sy*cz - sa*cy*sz;
        float by = ca*sy*sz - sa*cy*cz;
        gmA[q] = make_float2(ax, ay);
        gmB[q] = make_float2(bx, by);
    }
    __syncthreads();                                   // B1

    // ---- hoist ALL gate constants into registers and PIN them ----
    float2 GA[12], GB[12], GY[12];
#pragma unroll
    for (int q = 0; q < 12; ++q) {
        GA[q] = gmA[q];  PIN(GA[q]);
        GB[q] = gmB[q];  PIN(GB[q]);
        GY[q] = gyS[q];  PIN(GY[q]);
    }

    float2 v[16];

    // ---- init in layout C: L0 RX product state, ring0 folded ----
    // (R10-verified) i = P^{-1}(j), j = (t<<4)|r:
    //  i0=r0^r1 (q11), i1=r1^r2 (q10), i2=r2^r3 (q9), i3=r3^t0 (q8),
    //  i4..i9 = gray(t) bits 0..5 (qubits 7..2),
    //  i10 = t6^r0^t7 (q1), i11 = r0^t7 (q0)
    {
        const int g = (t ^ (t >> 1)) & 0x3F;
        float Pt = 1.0f;
#pragma unroll
        for (int m = 0; m < 6; ++m) {
            float2 cs = coI[7 - m];
            Pt *= ((g >> m) & 1) ? cs.y : cs.x;
        }
        const int ct = __popc(g);
        const int t0 = t & 1, t7 = (t >> 7) & 1;
        const int e1 = ((t >> 6) ^ (t >> 7)) & 1;
        float2 q11 = coI[11], q10 = coI[10], q9 = coI[9],
               q8 = coI[8], q1 = coI[1], q0 = coI[0];
        const float u8  = t0 ? q8.y : q8.x;     // qubit 8, key t0^r3
        const float u8n = t0 ? q8.x : q8.y;
        const float u1  = e1 ? q1.y : q1.x;     // qubit 1, key e1^r0
        const float u1n = e1 ? q1.x : q1.y;
        const float u0  = t7 ? q0.y : q0.x;     // qubit 0, key t7^r0
        const float u0n = t7 ? q0.x : q0.y;
#pragma unroll
        for (int r = 0; r < 16; ++r) {
            const int r0 = r & 1, r1 = (r >> 1) & 1, r2 = (r >> 2) & 1,
                      r3 = (r >> 3) & 1;
            const int b11 = r0 ^ r1, b10 = r1 ^ r2, b9 = r2 ^ r3;
            float m = Pt * (b11 ? q11.y : q11.x) * (b10 ? q10.y : q10.x)
                         * (b9 ? q9.y : q9.x) * (r3 ? u8n : u8)
                         * (r0 ? u1n : u1) * (r0 ? u0n : u0);
            int k = (ct + b11 + b10 + b9 + (r3 ^ t0) + (r0 ^ e1) + (r0 ^ t7)) & 3;
            v[r].x = (k == 0) ? m : ((k == 2) ? -m : 0.0f);
            v[r].y = (k == 3) ? m : ((k == 1) ? -m : 0.0f);
        }
    }

    // ---- fused M-pass (L0 RY,RZ + L1 RX), C -> B -> A ----
    M_PHASE(8);                       // qubits 8..11 in C
    LOCAL_X(ADDR_C, ADDR_B);          // X1: wave-local
    M_PHASE(4);                       // qubits 4..7  in B
#pragma unroll
    for (int r = 0; r < 16; ++r) S[ADDR_B(r)] = v[r];
    __syncthreads();                  // B2 (cross B -> A)
#pragma unroll
    for (int r = 0; r < 16; ++r) v[r] = S[ADDR_A(r)];
    M_PHASE(0);                       // qubits 0..3  in A

    // ---- layer-1 CNOT ring: A -> A (addr = Ft ^ const-folded G(r<<8)) ----
    __syncthreads();                  // B3 (all A-reads done before scatter)
#pragma unroll
    for (int r = 0; r < 16; ++r) {
        const int jr = r << 8;
        int yr = jr ^ (jr >> 1); yr ^= yr >> 2; yr ^= yr >> 4; yr ^= yr >> 8;
        const int pr = (yr & 0x7FF) | (((__popc(jr) ^ (jr >> 11)) & 1) << 11);
        const int Gr = (pr & ~15) | ((pr ^ (pr >> 4) ^ (pr >> 8)) & 15);
        S[Ft ^ Gr] = v[r];
    }
    __syncthreads();                  // B4
#pragma unroll
    for (int r = 0; r < 16; ++r) v[r] = S[ADDR_A(r)];

    // ---- layer-1 RY (final RZ dropped), A -> B -> C ----
    RY_PHASE(0);                      // in A
    // no barrier: store hits exactly the addresses THIS thread read at the
    // B4 gather; no other thread touches these slots (R2-verified).
#pragma unroll
    for (int r = 0; r < 16; ++r) S[ADDR_A(r)] = v[r];
    __syncthreads();                  // B5 (cross A -> B)
#pragma unroll
    for (int r = 0; r < 16; ++r) v[r] = S[ADDR_B(r)];
    RY_PHASE(4);                      // in B
    LOCAL_X(ADDR_B, ADDR_C);          // X5: wave-local
    RY_PHASE(8);                      // in C

    // ---- measurement in C ----
    // qubits 8..11 <-> r bits 3..0 ; qubits 2..7 <-> lane bits 5..0
    // (lane bit k = j[4+k] = qubit 7-k) ; qubits 0,1 <-> wave bits 1,0
    float p[16];
#pragma unroll
    for (int r = 0; r < 16; ++r)
        p[r] = fmaf(v[r].x, v[r].x, v[r].y * v[r].y);
    float sA[8], dA[8];
#pragma unroll
    for (int k = 0; k < 8; ++k) {
        sA[k] = p[2 * k] + p[2 * k + 1];
        dA[k] = p[2 * k] - p[2 * k + 1];
    }
    float z11 = ((dA[0] + dA[1]) + (dA[2] + dA[3]))
              + ((dA[4] + dA[5]) + (dA[6] + dA[7]));
    float sC[4], dC[4];
#pragma unroll
    for (int k = 0; k < 4; ++k) {
        sC[k] = sA[2 * k] + sA[2 * k + 1];
        dC[k] = sA[2 * k] - sA[2 * k + 1];
    }
    float z10 = (dC[0] + dC[1]) + (dC[2] + dC[3]);
    float e0 = sC[0] + sC[1], f0 = sC[0] - sC[1];
    float e1s = sC[2] + sC[3], f1 = sC[2] - sC[3];
    float vals[5];
    vals[0] = e0 + e1s;               // ptot
    vals[1] = e0 - e1s;               // z8  (r bit3)
    vals[2] = f0 + f1;                // z9  (r bit2)
    vals[3] = z10;                    // z10 (r bit1)
    vals[4] = z11;                    // z11 (r bit0)

    // 6-stage WHT butterfly: lane L ends with sum_l (-1)^{popc(L&l)} x_l
#pragma unroll
    for (int k = 0; k < 6; ++k) {
        const float sgn = ((l >> k) & 1) ? -1.f : 1.f;
#pragma unroll
        for (int m = 0; m < 5; ++m) {
            float tmp = __shfl_xor(vals[m], 1 << k, 64);
            vals[m] = fmaf(sgn, vals[m], tmp);
        }
    }
    if (l == 0) {                     // wave totals
        red[w * 12 + 0]  = vals[0];   // ptot (for qubits 0,1)
        red[w * 12 + 8]  = vals[1];
        red[w * 12 + 9]  = vals[2];
        red[w * 12 + 10] = vals[3];
        red[w * 12 + 11] = vals[4];
    } else if (__popc(l) == 1) {      // lane-bit sums: qubits 2..7
        int q = 8 - __ffs(l);         // l=1<<k -> q = 7-k
        red[w * 12 + q] = vals[0];
    }
    __syncthreads();                  // B6
    if (t < NQ) {
        float acc = 0.f;
#pragma unroll
        for (int ww = 0; ww < 4; ++ww) {
            if (t < 2) {
                float pv = red[ww * 12 + 0];
                acc += ((ww >> (1 - t)) & 1) ? -pv : pv;
            } else {
                acc += red[ww * 12 + t];
            }
        }
        out[b * NQ + t] = acc;
    }
}

extern "C" void kernel_launch(void* const* d_in, const int* in_sizes, int n_in,
                              void* d_out, int out_size, void* d_ws, size_t ws_size,
                              hipStream_t stream) {
    const int B = in_sizes[0] / NQ;  // 1024
    vqc_kernel<<<B, TPB, 0, stream>>>((const float*)d_in[0],
                                      (const float*)d_in[1],
                                      (const float*)d_in[2],
                                      (float*)d_out);
}